// Round 3
// baseline (112.644 us; speedup 1.0000x reference)
//
#include <hip/hip_runtime.h>
#include <math.h>

// StructureLoss — R10: two-pass streaming (drop the fused band).
// R9 post-mortem: 149KB LDS forced 1 block/CU; 8 waves barrier-locked 9x ->
// every latency exposed serially (dur 71us with HBM 7%, VALU 15%, occ 22% --
// all pipes idle). The LDS window is traffic-optimal but occupancy-fatal.
// R10: Pass A = vertical 31-box sums, thread-per-col, 32-deep register ring,
// 64-row segments; zero LDS, zero barriers, pure streaming (t 1.47x read,
// S 1x write). Pass B = R9's proven stage-2 (prefix + width-32 scan +
// neighbor shfl + fused elementwise), with q16 sourced from a coalesced
// GLOBAL read of S (S is L2/L3-hot, just written). No LDS march, no window,
// 1024 independent blocks, ~16 waves/CU. Summation order is bitwise
// identical to R9 (same 64-row segmentation), so absmax stays 0.

#define IMG_H 512
#define IMG_W 512
#define NB    32
#define HW    (IMG_H * IMG_W)
#define SEG   64              // rows per vert-pass block segment

__device__ __forceinline__ float wave_reduce(float v) {
#pragma unroll
  for (int off = 32; off > 0; off >>= 1) v += __shfl_down(v, off, 64);
  return v;
}

// ---- Pass A: S[r][c] = sum_{k=-15..15} t[clamp r+k][c] (zeros outside) ----
// 512 blocks: img(32) x colhalf(2) x rowseg(8). 256 threads, thread = 1 col.
__global__ __launch_bounds__(256, 4) void sloss_vert(const float* __restrict__ t,
                                                     float* __restrict__ S) {
  const int tid  = threadIdx.x;
  const int bid  = blockIdx.x;
  const int img  = bid >> 4;
  const int half = (bid >> 3) & 1;
  const int seg  = bid & 7;
  const int c    = half * 256 + tid;
  const int r0   = seg * SEG;             // multiple of 32 -> ring idx static
  const float* tc = t + (size_t)img * HW + c;
  float*       Sc = S + (size_t)img * HW + c;

  float win[32];
#pragma unroll
  for (int i = 0; i < 32; ++i) win[i] = 0.f;

  // warm-up: rows r0-15 .. r0+14 (ascending; same order as R9's warm-up)
  float sum = 0.f;
  {
    float w[30];
#pragma unroll
    for (int j = 0; j < 30; ++j) {
      int r = r0 - 15 + j;
      w[j] = ((unsigned)r < IMG_H) ? tc[(size_t)r * IMG_W] : 0.f;
    }
#pragma unroll
    for (int j = 0; j < 30; ++j) {
      sum += w[j];
      win[(j + 17) & 31] = w[j];          // slot for row r0-15+j
    }
  }

  // march 64 rows in 4 batches of 16: loads issued ahead, ring gives tails
#pragma unroll
  for (int bch = 0; bch < 4; ++bch) {
    float h[16];
#pragma unroll
    for (int j = 0; j < 16; ++j) {
      int r = r0 + bch * 16 + j + 15;
      h[j] = (r < IMG_H) ? tc[(size_t)r * IMG_W] : 0.f;
    }
#pragma unroll
    for (int j = 0; j < 16; ++j) {
      const int rr = bch * 16 + j;        // 0..63 (compile-time)
      sum += h[j];
      Sc[(size_t)(r0 + rr) * IMG_W] = sum;
      sum -= win[(rr + 17) & 31];         // row r0+rr-15
      win[(rr + 15) & 31] = h[j];         // row r0+rr+15
    }
  }
}

// ---- Pass B: horizontal box from S + fused elementwise + block reduce ----
// 1024 blocks: img(32) x grp(32 of 16 rows). 512 threads: row=tid>>5 (16),
// sub=tid&31 (16-col chunk). All operands read streaming from global.
__global__ __launch_bounds__(512, 4) void sloss_fuse(const float* __restrict__ x,
                                                     const float* __restrict__ t,
                                                     const float* __restrict__ S,
                                                     float* __restrict__ part) {
  __shared__ float red[8][4];
  const int tid = threadIdx.x;
  const int gid = blockIdx.x;
  const int img = gid >> 5;
  const int grp = gid & 31;
  const int r0  = grp * 16;
  const int row = tid >> 5;
  const int sub = tid & 31;
  const size_t base = (size_t)img * HW + (size_t)(r0 + row) * IMG_W + 16 * sub;

  // issue all 24 loads up front; scan latency covers x/t arrival
  float4 sg[4], xg[4], tg[4];
#pragma unroll
  for (int e = 0; e < 4; ++e) sg[e] = *(const float4*)(S + base + 4 * e);
#pragma unroll
  for (int e = 0; e < 4; ++e) xg[e] = *(const float4*)(x + base + 4 * e);
#pragma unroll
  for (int e = 0; e < 4; ++e) tg[e] = *(const float4*)(t + base + 4 * e);

  // thread-local prefix over 16 cols
  float q16[16];
  {
    float run = 0.f;
#pragma unroll
    for (int e = 0; e < 4; ++e) {
      q16[4 * e + 0] = run + sg[e].x;
      q16[4 * e + 1] = q16[4 * e + 0] + sg[e].y;
      q16[4 * e + 2] = q16[4 * e + 1] + sg[e].z;
      q16[4 * e + 3] = q16[4 * e + 2] + sg[e].w;
      run = q16[4 * e + 3];
    }
  }
  // width-32 segmented inclusive scan of chunk totals (2 rows per wave)
  {
    float tot = q16[15], ss = tot;
#pragma unroll
    for (int d = 1; d < 32; d <<= 1) {
      float uu = __shfl_up(ss, d, 64);
      if (sub >= d) ss += uu;
    }
    float pb = ss - tot;
#pragma unroll
    for (int j = 0; j < 16; ++j) q16[j] += pb;   // q16[j] = P[16*sub + j]
  }

  const float inv_area = 1.0f / 961.0f;
  float aW = 0.f, aWB = 0.f, aI = 0.f, aU = 0.f;
#pragma unroll
  for (int e = 0; e < 4; ++e) {
    float xa[4] = {xg[e].x, xg[e].y, xg[e].z, xg[e].w};
    float ta[4] = {tg[e].x, tg[e].y, tg[e].z, tg[e].w};
#pragma unroll
    for (int l = 0; l < 4; ++l) {
      const int j = 4 * e + l;
      float hi;
      if (j == 0) {
        hi = q16[15];
      } else {
        float gd = __shfl_down(q16[j - 1], 1, 64);
        hi = (sub == 31) ? q16[15] : gd;           // P[min(c+15,511)]
      }
      float gu = __shfl_up(q16[j], 1, 64);
      float lo = (sub == 0) ? 0.f : gu;            // P[c-16] or 0
      float box = hi - lo;
      float tv = ta[l], xv = xa[l];
      float w   = fmaf(5.0f, fabsf(box * inv_area - tv), 1.0f);
      float ez  = __expf(-fabsf(xv));
      float iv  = 1.0f / (1.0f + ez);
      float p   = (xv >= 0.f) ? iv : ez * iv;      // sigmoid(x)
      float bce = fmaxf(xv, 0.f) - xv * tv + __logf(1.0f + ez);
      aW  += w;
      aWB = fmaf(w, bce, aWB);
      aI  = fmaf(p * tv, w, aI);
      aU  = fmaf(p + tv, w, aU);
    }
  }

  aW  = wave_reduce(aW);
  aWB = wave_reduce(aWB);
  aI  = wave_reduce(aI);
  aU  = wave_reduce(aU);
  const int wv = tid >> 6, ln = tid & 63;
  if (ln == 0) { red[wv][0] = aW; red[wv][1] = aWB; red[wv][2] = aI; red[wv][3] = aU; }
  __syncthreads();
  if (tid < 4) {
    float v = 0.f;
#pragma unroll
    for (int w8 = 0; w8 < 8; ++w8) v += red[w8][tid];
    part[(img * 32 + grp) * 4 + tid] = v;
  }
}

// ---- finalize: reduce 1024 block-partials -> scalar loss ----
__global__ void sloss_final(const float* __restrict__ part,
                            float* __restrict__ out) {
  __shared__ float s[128];
  int tid = threadIdx.x;          // 128 threads
  int img = tid >> 2, q = tid & 3;
  float v = 0.f;
#pragma unroll 4
  for (int g = 0; g < 32; ++g) v += part[((img << 5) + g) * 4 + q];
  s[tid] = v;
  __syncthreads();
  float loss = 0.f;
  if (tid < NB) {
    float aW  = s[tid * 4 + 0];
    float aWB = s[tid * 4 + 1];
    float aI  = s[tid * 4 + 2];
    float aU  = s[tid * 4 + 3];
    loss = aWB / aW + 1.0f - (aI + 1.0f) / (aU - aI + 1.0f);
  }
  loss = wave_reduce(loss);
  if (tid == 0) out[0] = loss * (1.0f / (float)NB);
}

extern "C" void kernel_launch(void* const* d_in, const int* in_sizes, int n_in,
                              void* d_out, int out_size, void* d_ws, size_t ws_size,
                              hipStream_t stream) {
  const float* x = (const float*)d_in[0];
  const float* t = (const float*)d_in[1];
  float* S    = (float*)d_ws;                      // 32*512*512 f32 = 33.5 MB
  float* part = (float*)d_ws + (size_t)NB * HW;    // 1024 x 4 f32

  sloss_vert<<<512, 256, 0, stream>>>(t, S);
  sloss_fuse<<<1024, 512, 0, stream>>>(x, t, S, part);
  sloss_final<<<1, 128, 0, stream>>>(part, (float*)d_out);
}